// Round 20
// baseline (194.836 us; speedup 1.0000x reference)
//
#include <hip/hip_runtime.h>
#include <hip/hip_bf16.h>

#define T_OBS 16
#define NAg   4096
#define Vn    8
#define NV    32768           // NAg*Vn
#define SEQ   36864           // NAg + NV
#define PRED  25

typedef __bf16 bf16x8 __attribute__((ext_vector_type(8)));
typedef float  f32x4  __attribute__((ext_vector_type(4)));

// light barrier: LDS-only drain, leaves vmcnt (global loads/stores) in flight.
#define LBAR() do {                                        \
    asm volatile("s_waitcnt lgkmcnt(0)" ::: "memory");     \
    __builtin_amdgcn_s_barrier();                          \
    __builtin_amdgcn_sched_barrier(0);                     \
  } while (0)

__device__ __forceinline__ float leakyf(float v){ return v >= 0.f ? v : 0.1f*v; }
// fast sigmoid/tanh: v_rcp_f32 (~1 ulp) instead of IEEE divide (~10 instrs)
__device__ __forceinline__ float sigf(float x){
  return __builtin_amdgcn_rcpf(1.f + __expf(-x));
}
__device__ __forceinline__ float tanh2f(float x){
  return fmaf(2.f, __builtin_amdgcn_rcpf(1.f + __expf(-2.f*x)), -1.f);
}
__device__ __forceinline__ float tanhf_(float x){
  x = fminf(fmaxf(x, -10.f), 10.f);
  float e = __expf(2.f*x);
  return (e-1.f)*__builtin_amdgcn_rcpf(e+1.f);
}
__device__ __forceinline__ float bf2f(unsigned short u){
  union{unsigned int i; float f;} v; v.i = ((unsigned int)u)<<16; return v.f;
}
__device__ __forceinline__ unsigned short f2bf(float f){
  __hip_bfloat16 b = __float2bfloat16(f);
  return *reinterpret_cast<unsigned short*>(&b);
}
__device__ __forceinline__ float dot4f(float4 a, float4 b, float acc){
  return fmaf(a.x,b.x, fmaf(a.y,b.y, fmaf(a.z,b.z, fmaf(a.w,b.w, acc))));
}
__device__ __forceinline__ bf16x8 as_bf16x8(uint4 u){
  union { uint4 a; bf16x8 b; } v; v.a = u; return v.b;
}
__device__ __forceinline__ uint4 pack8bf(float4 a, float4 b){
  union{ unsigned short s[8]; uint4 u; } o;
  o.s[0]=f2bf(a.x); o.s[1]=f2bf(a.y); o.s[2]=f2bf(a.z); o.s[3]=f2bf(a.w);
  o.s[4]=f2bf(b.x); o.s[5]=f2bf(b.y); o.s[6]=f2bf(b.z); o.s[7]=f2bf(b.w);
  return o.u;
}

// ---------------------------------------------------------------------------
// Decode bool masks -> per-agent 8 cell indices (validated R15, wave/agent).
// ---------------------------------------------------------------------------
__global__ void k_decode_masks(const void* __restrict__ masks, int* __restrict__ cells){
  const int tid = threadIdx.x;
  const int a   = tid >> 6;          // wave in block (4 agents/block)
  const int l   = tid & 63;
  const int n   = blockIdx.x*4 + a;
  const unsigned char* m8  = (const unsigned char*)masks;
  const int*           m32 = (const int*)masks;
  bool sel8 = false, sel32 = false;
  if (l < 39){
    size_t base = ((size_t)n*39 + l)*64;
    sel8  = m8[base] && m8[base+1] && m8[base+33];
    sel32 = m32[base] != 0;
  }
  unsigned long long b8  = __ballot(sel8);
  unsigned long long b32 = __ballot(sel32);
  unsigned long long m = (__popcll(b8) == 8) ? b8 : b32;
  int cnt = __popcll(m);
  if (l < 8 && l >= cnt) cells[n*8 + l] = 0;           // default fill (disjoint slots)
  bool sel = (m >> l) & 1ull;
  int prefix = __popcll(m & ((1ull << l) - 1ull));
  if (sel && prefix < 8) cells[n*8 + prefix] = l;
}

// ---------------------------------------------------------------------------
// One-shot weight re-layouts (validated R14).
// ---------------------------------------------------------------------------
__global__ void k_prep(const float* __restrict__ eWih, const float* __restrict__ eWhh,
                       unsigned short* __restrict__ Wpk,
                       const float* __restrict__ dWhh, unsigned short* __restrict__ WdecF,
                       const float* __restrict__ outW, unsigned short* __restrict__ WoutF,
                       const float* __restrict__ sW, unsigned short* __restrict__ SWF,
                       const float* __restrict__ socW, unsigned short* __restrict__ WsocF,
                       const float* __restrict__ dWih, unsigned short* __restrict__ WdihF){
  int idx = blockIdx.x*blockDim.x + threadIdx.x;   // 49152 threads
  if (idx < 24576){                                // encoder: 48 frags * 512
    int f   = idx >> 9;
    int rem = idx & 511;
    int l   = rem >> 3, j = rem & 7;
    int lr  = l & 15, lg = l >> 4;
    float val;
    if (f < 32){
      int nt = f >> 2, kk = f & 3;
      int n  = nt*16 + lr;                         // rows 0..127 = r,z gates
      int k  = kk*32 + lg*8 + j;
      val = (k < 64) ? eWih[(size_t)n*64 + k] : eWhh[(size_t)n*64 + (k-64)];
    } else if (f < 40){
      int q = f - 32;
      int n = (8 + (q>>1))*16 + lr;                // rows 128..191 = n gate
      int k = (q&1)*32 + lg*8 + j;
      val = eWih[(size_t)n*64 + k];
    } else {
      int q = f - 40;
      int n = (8 + (q>>1))*16 + lr;
      int k = (q&1)*32 + lg*8 + j;
      val = eWhh[(size_t)n*64 + k];
    }
    Wpk[f*512 + l*8 + j] = f2bf(val);
  }
  if (idx < 49152){                                // decoder Whh: 96 frags * 512
    int f   = idx >> 9;                            // g*12 + gate*4 + kk
    int rem = idx & 511;
    int l   = rem >> 3, j = rem & 7;
    int lr  = l & 15, lg = l >> 4;
    int g = f/12, loc = f%12, gate = loc>>2, kk = loc&3;
    int n = gate*128 + g*16 + lr;
    int k = kk*32 + lg*8 + j;
    WdecF[idx] = f2bf(dWhh[(size_t)n*128 + k]);
  }
  if (idx < 49152){                                // decoder Wih: 96 frags * 512
    int f   = idx >> 9;                            // g*12 + gate*4 + kk
    int rem = idx & 511;
    int l   = rem >> 3, j = rem & 7;
    int lr  = l & 15, lg = l >> 4;
    int g = f/12, loc = f%12, gate = loc>>2, kk = loc&3;
    int n = gate*128 + g*16 + lr;
    int k = kk*32 + lg*8 + j;
    WdihF[idx] = (k < 112) ? f2bf(dWih[(size_t)n*112 + k]) : (unsigned short)0;
  }
  if (idx < 2048){                                 // out head: 4 frags * 512
    int kk  = idx >> 9;
    int rem = idx & 511;
    int l   = rem >> 3, j = rem & 7;
    int lr  = l & 15, lg = l >> 4;
    int k = kk*32 + lg*8 + j;
    float v = (lr < 5) ? outW[(size_t)lr*128 + k] : 0.f;
    WoutF[idx] = f2bf(v);
  }
  if (idx < 8192){                                 // s_W: 16 frags * 512
    int f   = idx >> 9;                            // nt*2 + kk
    int rem = idx & 511;
    int l   = rem >> 3, j = rem & 7;
    int lr  = l & 15, lg = l >> 4;
    int nt = f >> 1, kk = f & 1;
    int nn = nt*16 + lr;
    int k  = kk*32 + lg*8 + j;
    SWF[idx] = f2bf(sW[(size_t)nn*64 + k]);
  }
  if (idx < 36864){                                // soc conv1: 72 frags * 512
    int f   = idx >> 9;                            // (w*9+kk)*2+ks
    int rem = idx & 511;
    int l   = rem >> 3, j = rem & 7;
    int lr  = l & 15, lg = l >> 4;
    int w = f/18, loc = f%18, kk = loc>>1, ks = loc&1;
    int o = w*16 + lr;
    int c = ks*32 + lg*8 + j;
    WsocF[idx] = f2bf(socW[(size_t)o*576 + c*9 + kk]);
  }
}

// ---------------------------------------------------------------------------
// x_e = leaky(x @ dyn_W.T + dyn_b) -> E (bf16). One thread per (t,s,c8).
// ---------------------------------------------------------------------------
__global__ void k_embed_x(const float* __restrict__ x, const float* __restrict__ dynW,
                          const float* __restrict__ dynb, __hip_bfloat16* __restrict__ E){
  __shared__ float2 dwL[64];
  __shared__ float  dbL[64];
  const int tid = threadIdx.x;
  if (tid < 64){ dwL[tid] = *(const float2*)(dynW + tid*2); dbL[tid] = dynb[tid]; }
  __syncthreads();

  int idx = blockIdx.x*256 + tid;                  // 16*4096*8 exactly
  int c8 = idx & 7;
  int s  = (idx >> 3) & 4095;
  int t  = idx >> 15;
  float2 xy = *(const float2*)(x + ((size_t)t*NAg + s)*2);
  union { unsigned short sh[8]; uint4 u; } ou;
  #pragma unroll
  for (int jj=0; jj<8; ++jj){
    int c = c8*8 + jj;
    ou.sh[jj] = f2bf(leakyf(fmaf(xy.x, dwL[c].x, fmaf(xy.y, dwL[c].y, dbL[c]))));
  }
  *(uint4*)((unsigned short*)E + ((size_t)t*SEQ + s)*64 + c8*8) = ou.u;
}

// ---------------------------------------------------------------------------
// Per agent n (fused, MFMA): ng_e -> H = ng_e@sW.T+sb -> graph einsum -> E.
// R19: einsum result staged in LDS [16 t][8 wv][64 c] then emitted as ONE
// contiguous 1KB store per wave per t (write-coalescing fix; 128B scattered
// chunks -> 1KB linear). Numerically identical to R18.
// ---------------------------------------------------------------------------
__global__ __launch_bounds__(256,2) void k_embed_agg_mfma(
    const float* __restrict__ ngbrs, const float* __restrict__ graphs,
    const float* __restrict__ dynW, const float* __restrict__ dynb,
    const unsigned short* __restrict__ SWF, const float* __restrict__ sb,
    __hip_bfloat16* __restrict__ E)
{
  __shared__ __align__(16) unsigned char smem[128*138*2];  // 35.3 KB union region
  __shared__ float2 pL[128];
  __shared__ __align__(16) float gL[128];
  __shared__ float2 dwL[64];
  __shared__ float  dbL[64];
  unsigned char*  ngeb = smem;                  // bf16 [row][64] swizzled (16 KB), GEMM phase
  unsigned short* hmb  = (unsigned short*)smem; // bf16 [tv][138], einsum phase
  unsigned short* stg  = (unsigned short*)smem; // bf16 [16 t][512], output stage (16 KB)
  const int tid = threadIdx.x;
  const int n = blockIdx.x;

  if (tid < 128) gL[tid] = graphs[(size_t)n*128 + tid];
  if (tid < 64)  dwL[tid] = *(const float2*)(dynW + tid*2);
  if (tid < 64)  dbL[tid] = dynb[tid];
  if (tid < 128){
    int t = tid >> 3, v = tid & 7;
    pL[tid] = *(const float2*)(ngbrs + ((size_t)t*NV + (size_t)n*8 + v)*2);
  }
  __syncthreads();

  #pragma unroll
  for (int p=0; p<4; ++p){
    int chunk = tid + p*256;          // 1024: row*8 + c8
    int row = chunk >> 3, c8 = chunk & 7;
    float2 xy = pL[row];
    union { unsigned short s[8]; uint4 u; } ou;
    #pragma unroll
    for (int jj=0; jj<8; ++jj){
      int c = c8*8 + jj;
      ou.s[jj] = f2bf(leakyf(fmaf(xy.x, dwL[c].x, fmaf(xy.y, dwL[c].y, dbL[c]))));
    }
    *(uint4*)(ngeb + ((row*128 + c8*16) ^ ((row&7)<<4))) = ou.u;
  }
  __syncthreads();

  const int w4 = tid >> 6, l = tid & 63, lr = l & 15, lg = l >> 4;
  f32x4 acc[2][8];
  {
    uint4 bsw[16];
    #pragma unroll
    for (int f=0; f<16; ++f) bsw[f] = *(const uint4*)(SWF + f*512 + l*8);
    float sbv[8];
    #pragma unroll
    for (int nt=0; nt<8; ++nt) sbv[nt] = sb[nt*16 + lr];

    #pragma unroll
    for (int m=0; m<2; ++m)
      #pragma unroll
      for (int nt=0; nt<8; ++nt)
        acc[m][nt] = (f32x4){sbv[nt], sbv[nt], sbv[nt], sbv[nt]};

    #pragma unroll
    for (int m=0; m<2; ++m){
      int row = (w4*2+m)*16 + lr;
      int rb = row*128, sz = (row&7)<<4;
      uint4 a0 = *(const uint4*)(ngeb + ((rb      + lg*16) ^ sz));
      uint4 a1 = *(const uint4*)(ngeb + ((rb + 64 + lg*16) ^ sz));
      bf16x8 A0 = as_bf16x8(a0), A1 = as_bf16x8(a1);
      #pragma unroll
      for (int nt=0; nt<8; ++nt){
        acc[m][nt] = __builtin_amdgcn_mfma_f32_16x16x32_bf16(A0, as_bf16x8(bsw[nt*2+0]), acc[m][nt], 0,0,0);
        acc[m][nt] = __builtin_amdgcn_mfma_f32_16x16x32_bf16(A1, as_bf16x8(bsw[nt*2+1]), acc[m][nt], 0,0,0);
      }
    }
  }
  __syncthreads();                       // all ngeb reads complete; region -> hmb

  #pragma unroll
  for (int m=0; m<2; ++m)
    #pragma unroll
    for (int nt=0; nt<8; ++nt)
      #pragma unroll
      for (int jj=0; jj<4; ++jj)
        hmb[((w4*2+m)*16 + lg*4 + jj)*138 + nt*16 + lr] = f2bf(acc[m][nt][jj]);
  __syncthreads();

  // einsum: thread (t = tid>>4, c4 = tid&15); 8 wv outputs of 4 floats each
  {
    int t = tid >> 4, c4 = tid & 15;
    float a4[8][4];
    #pragma unroll
    for (int wv=0; wv<8; ++wv)
      #pragma unroll
      for (int jo=0; jo<4; ++jo) a4[wv][jo] = 0.f;

    #pragma unroll
    for (int k=0; k<2; ++k)
      #pragma unroll
      for (int v=0; v<8; ++v){
        uint2 hu = *(const uint2*)(hmb + (t*8+v)*138 + k*64 + c4*4);
        const unsigned short* hs = (const unsigned short*)&hu;
        float h0 = bf2f(hs[0]), h1 = bf2f(hs[1]), h2 = bf2f(hs[2]), h3 = bf2f(hs[3]);
        float4 g0 = *(const float4*)(gL + k*64 + v*8);
        float4 g1 = *(const float4*)(gL + k*64 + v*8 + 4);
        const float* ga = &g0.x;
        const float* gb = &g1.x;
        #pragma unroll
        for (int q=0; q<4; ++q){
          a4[q][0]   = fmaf(ga[q], h0, a4[q][0]);
          a4[q][1]   = fmaf(ga[q], h1, a4[q][1]);
          a4[q][2]   = fmaf(ga[q], h2, a4[q][2]);
          a4[q][3]   = fmaf(ga[q], h3, a4[q][3]);
          a4[4+q][0] = fmaf(gb[q], h0, a4[4+q][0]);
          a4[4+q][1] = fmaf(gb[q], h1, a4[4+q][1]);
          a4[4+q][2] = fmaf(gb[q], h2, a4[4+q][2]);
          a4[4+q][3] = fmaf(gb[q], h3, a4[4+q][3]);
        }
      }

    __syncthreads();                   // all hmb reads done; region -> stg

    #pragma unroll
    for (int wv=0; wv<8; ++wv){
      union { unsigned short s[4]; uint2 u; } ou;
      ou.s[0] = f2bf(a4[wv][0]); ou.s[1] = f2bf(a4[wv][1]);
      ou.s[2] = f2bf(a4[wv][2]); ou.s[3] = f2bf(a4[wv][3]);
      *(uint2*)(stg + t*512 + wv*64 + c4*4) = ou.u;
    }
  }
  __syncthreads();

  // coalesced emit: wave wv64 writes t = wv64*4+it as one 1KB contiguous store
  {
    int wv64 = tid >> 6;
    int l2   = tid & 63;
    unsigned short* Eu = (unsigned short*)E;
    #pragma unroll
    for (int it=0; it<4; ++it){
      int t = wv64*4 + it;
      uint4 v = *(const uint4*)(stg + t*512 + l2*8);
      *(uint4*)(Eu + ((size_t)t*SEQ + NAg + (size_t)n*8)*64 + l2*8) = v;
    }
  }
}

// ---------------------------------------------------------------------------
// Encoder GRU via MFMA, full-gate-per-wave partition (validated R7/R9/R10).
// ---------------------------------------------------------------------------
__global__ __launch_bounds__(256,4) void k_gru_enc_mfma(
    const unsigned short* __restrict__ E,
    const unsigned short* __restrict__ Wpk,
    const float* __restrict__ bih, const float* __restrict__ bhh,
    float* __restrict__ h_all)
{
  __shared__ __align__(16) unsigned char Hb[2][2048];
  const int tid = threadIdx.x;
  const int w  = tid >> 6;         // wave 0..3
  const int l  = tid & 63;
  const int lr = l & 15;           // A row (seq) / D col
  const int lg = l >> 4;
  const size_t s0 = (size_t)blockIdx.x * 16;
  const int i  = w*16 + lr;        // owned h column

  uint4 bf[12];
  #pragma unroll
  for (int q=0; q<4; ++q) bf[q]   = *(const uint4*)(Wpk + (4*w + q)*512 + l*8);
  #pragma unroll
  for (int q=0; q<4; ++q) bf[4+q] = *(const uint4*)(Wpk + (16 + 4*w + q)*512 + l*8);
  #pragma unroll
  for (int q=0; q<2; ++q) bf[8+q] = *(const uint4*)(Wpk + (32 + 2*w + q)*512 + l*8);
  #pragma unroll
  for (int q=0; q<2; ++q) bf[10+q]= *(const uint4*)(Wpk + (40 + 2*w + q)*512 + l*8);

  const float b_r = bih[i]     + bhh[i];
  const float b_z = bih[64+i]  + bhh[64+i];
  const float bni = bih[128+i];
  const float bnh = bhh[128+i];

  *(uint4*)(&Hb[0][0] + tid*16) = make_uint4(0,0,0,0);
  __syncthreads();

  float hreg[4] = {0.f,0.f,0.f,0.f};

  const int swz = (lr & 7) << 4;
  const int rd0 = (lr*128      + lg*16) ^ swz;
  const int rd1 = (lr*128 + 64 + lg*16) ^ swz;
  int wro[4];
  #pragma unroll
  for (int u=0; u<4; ++u){
    int s = lg*4 + u;
    wro[u] = (s*128 + i*2) ^ ((s & 7) << 4);
  }

  const unsigned short* ep = E + (s0 + lr)*64 + lg*8;
  uint4 ax0 = *(const uint4*)(ep);
  uint4 ax1 = *(const uint4*)(ep + 32);

  int cur = 0;

  #pragma unroll 1
  for (int t=0; t<T_OBS; ++t){
    const unsigned short* pn = ep + ((t < 15) ? (size_t)SEQ*64 : 0);
    uint4 nx0 = *(const uint4*)(pn);
    uint4 nx1 = *(const uint4*)(pn + 32);

    const unsigned char* hc = Hb[cur];
    uint4 ah0 = *(const uint4*)(hc + rd0);
    uint4 ah1 = *(const uint4*)(hc + rd1);

    bf16x8 Ax0 = as_bf16x8(ax0), Ax1 = as_bf16x8(ax1);
    bf16x8 Ah0 = as_bf16x8(ah0), Ah1 = as_bf16x8(ah1);

    f32x4 z4 = (f32x4){0.f,0.f,0.f,0.f};
    f32x4 aRx = z4, aRh = z4, aZx = z4, aZh = z4, aNI = z4, aNH = z4;

    aRx = __builtin_amdgcn_mfma_f32_16x16x32_bf16(Ax0, as_bf16x8(bf[0]),  aRx, 0,0,0);
    aRx = __builtin_amdgcn_mfma_f32_16x16x32_bf16(Ax1, as_bf16x8(bf[1]),  aRx, 0,0,0);
    aRh = __builtin_amdgcn_mfma_f32_16x16x32_bf16(Ah0, as_bf16x8(bf[2]),  aRh, 0,0,0);
    aRh = __builtin_amdgcn_mfma_f32_16x16x32_bf16(Ah1, as_bf16x8(bf[3]),  aRh, 0,0,0);
    aZx = __builtin_amdgcn_mfma_f32_16x16x32_bf16(Ax0, as_bf16x8(bf[4]),  aZx, 0,0,0);
    aZx = __builtin_amdgcn_mfma_f32_16x16x32_bf16(Ax1, as_bf16x8(bf[5]),  aZx, 0,0,0);
    aZh = __builtin_amdgcn_mfma_f32_16x16x32_bf16(Ah0, as_bf16x8(bf[6]),  aZh, 0,0,0);
    aZh = __builtin_amdgcn_mfma_f32_16x16x32_bf16(Ah1, as_bf16x8(bf[7]),  aZh, 0,0,0);
    aNI = __builtin_amdgcn_mfma_f32_16x16x32_bf16(Ax0, as_bf16x8(bf[8]),  aNI, 0,0,0);
    aNI = __builtin_amdgcn_mfma_f32_16x16x32_bf16(Ax1, as_bf16x8(bf[9]),  aNI, 0,0,0);
    aNH = __builtin_amdgcn_mfma_f32_16x16x32_bf16(Ah0, as_bf16x8(bf[10]), aNH, 0,0,0);
    aNH = __builtin_amdgcn_mfma_f32_16x16x32_bf16(Ah1, as_bf16x8(bf[11]), aNH, 0,0,0);

    f32x4 aR = aRx + aRh;
    f32x4 aZ = aZx + aZh;

    unsigned char* hn = Hb[cur^1];
    #pragma unroll
    for (int u=0; u<4; ++u){
      float r  = sigf(aR[u] + b_r);
      float z  = sigf(aZ[u] + b_z);
      float nn = tanh2f(fmaf(r, aNH[u] + bnh, aNI[u] + bni));
      float h  = fmaf(z, hreg[u] - nn, nn);
      hreg[u]  = h;
      *(unsigned short*)(hn + wro[u]) = f2bf(h);
    }
    LBAR();
    cur ^= 1;
    ax0 = nx0; ax1 = nx1;
    ep = pn;
  }

  #pragma unroll
  for (int u=0; u<4; ++u)
    h_all[(s0 + lg*4 + u)*64 + i] = hreg[u];
}

// ---------------------------------------------------------------------------
// Social branch via MFMA (validated R5) + fused x_s head.
// ---------------------------------------------------------------------------
__global__ __launch_bounds__(256,3) void k_soc_mfma(
    const float* __restrict__ h_all, const int* __restrict__ cells,
    const unsigned short* __restrict__ WsocF, const float* __restrict__ socb,
    const float* __restrict__ c31W, const float* __restrict__ c31b,
    const float* __restrict__ hidW, const float* __restrict__ hidb,
    float* __restrict__ xc)
{
  __shared__ unsigned short Qb[9*8*64];   // 9 KB  [kk][v][o] bf16
  __shared__ float o1p[4*64*17];          // 17 KB scatter partials (y shifted +2)
  __shared__ float o1[64*12];             // 3 KB  out1 (y 0..10)
  __shared__ float c2p[4*144];            // 2.25 KB conv2 partials
  __shared__ float W2L[64*48];            // 12 KB [o][ky][p]
  __shared__ float socbL[64];
  __shared__ float b2L[16];
  __shared__ int   cellsL[64];            // [a][v]

  const int tid = threadIdx.x;
  const int w  = tid >> 6;
  const int l  = tid & 63;
  const int lr = l & 15, lg = l >> 4;
  const int n0 = blockIdx.x * 8;

  // fused x_s = leaky(h_x @ hid_W.T + hid_b) for this block's 8 agents
  {
    int a = tid >> 5, j = tid & 31;
    const float* h = h_all + (size_t)(n0 + a)*64;
    const float* wv = hidW + (size_t)j*64;
    float acc = hidb[j];
    #pragma unroll
    for (int k4=0; k4<16; ++k4)
      acc = dot4f(*(const float4*)(h + k4*4), *(const float4*)(wv + k4*4), acc);
    xc[(size_t)(n0+a)*112 + j] = leakyf(acc);
  }

  for (int idx=tid; idx<3072; idx+=256){
    int p = idx/192, rem = idx%192, o = rem/3, ky = rem%3;
    W2L[(o*3+ky)*16 + p] = c31W[idx];
  }
  if (tid < 64) socbL[tid] = socb[tid];
  if (tid < 16) b2L[tid]  = c31b[tid];
  if (tid < 64) cellsL[tid] = cells[n0*8 + tid];

  uint4 bs[18];
  #pragma unroll
  for (int f=0; f<18; ++f)
    bs[f] = *(const uint4*)(WsocF + (size_t)(w*18 + f)*512 + l*8);
  __syncthreads();

  #pragma unroll 1
  for (int a=0; a<8; ++a){
    uint4 ax0u = make_uint4(0,0,0,0), ax1u = make_uint4(0,0,0,0);
    if (lr < 8){
      const float* hp = h_all + ((size_t)NAg + (size_t)(n0+a)*8 + lr)*64 + lg*8;
      float4 f0 = *(const float4*)(hp);
      float4 f1 = *(const float4*)(hp + 4);
      float4 f2 = *(const float4*)(hp + 32);
      float4 f3 = *(const float4*)(hp + 36);
      ax0u = pack8bf(f0, f1);
      ax1u = pack8bf(f2, f3);
    }
    bf16x8 A0 = as_bf16x8(ax0u), A1 = as_bf16x8(ax1u);

    f32x4 acc[9];
    #pragma unroll
    for (int kk=0; kk<9; ++kk) acc[kk] = (f32x4){0.f,0.f,0.f,0.f};
    #pragma unroll
    for (int kk=0; kk<9; ++kk){
      acc[kk] = __builtin_amdgcn_mfma_f32_16x16x32_bf16(A0, as_bf16x8(bs[kk*2+0]), acc[kk], 0,0,0);
      acc[kk] = __builtin_amdgcn_mfma_f32_16x16x32_bf16(A1, as_bf16x8(bs[kk*2+1]), acc[kk], 0,0,0);
    }

    __syncthreads();

    if (lg < 2){
      #pragma unroll
      for (int kk=0; kk<9; ++kk)
        #pragma unroll
        for (int j=0; j<4; ++j)
          Qb[(kk*8 + lg*4 + j)*64 + w*16 + lr] = f2bf(acc[kk][j]);
    }
    for (int idx=tid; idx<2816; idx+=256){
      int q = idx/704, r = idx%704;
      int o = r/11, y = r%11;
      o1p[(q*64 + o)*17 + y + 2] = 0.f;
    }
    __syncthreads();

    {
      int o = tid & 63, q = tid >> 6;
      #pragma unroll
      for (int p6=0; p6<6; ++p6){
        int pr = q*6 + p6;
        int v = pr/3, ky = pr%3;
        int cc = cellsL[a*8 + v];
        int gw = cc/13, gh = cc - gw*13;
        float val = bf2f(Qb[((ky*3+gw)*8 + v)*64 + o]);
        o1p[(q*64 + o)*17 + (gh - ky + 2)] += val;
      }
    }
    __syncthreads();

    for (int idx=tid; idx<704; idx+=256){
      int o = idx/11, y = idx%11;
      float s = socbL[o];
      #pragma unroll
      for (int q=0; q<4; ++q) s += o1p[(q*64 + o)*17 + y + 2];
      o1[o*12 + y] = leakyf(s);
    }
    __syncthreads();

    {
      int q = tid >> 6, l2 = tid & 63;
      for (int e=l2; e<144; e+=64){
        int p = e & 15, y2 = e >> 4;
        float accv = 0.f;
        #pragma unroll
        for (int oi=0; oi<16; ++oi){
          int oo = q*16 + oi;
          const float* o1r = o1 + oo*12 + y2;
          const float* w2r = W2L + oo*48 + p;
          accv = fmaf(o1r[0], w2r[0], fmaf(o1r[1], w2r[16], fmaf(o1r[2], w2r[32], accv)));
        }
        c2p[q*144 + e] = accv;
      }
    }
    __syncthreads();

    if (tid < 80){
      int p = tid/5, ww = tid%5;
      float v0, v1;
      {
        int y2 = (ww == 0) ? 0 : 2*ww - 1;
        float s = b2L[p];
        #pragma unroll
        for (int q=0; q<4; ++q) s += c2p[q*144 + y2*16 + p];
        v0 = leakyf(s);
      }
      if (ww == 0) v1 = v0;
      else {
        int y2 = 2*ww;
        float s = b2L[p];
        #pragma unroll
        for (int q=0; q<4; ++q) s += c2p[q*144 + y2*16 + p];
        v1 = leakyf(s);
      }
      xc[(size_t)(n0+a)*112 + 32 + p*5 + ww] = fmaxf(v0, v1);
    }
  }
}

// ---------------------------------------------------------------------------
// Decoder GRU via MFMA (validated R14: gi via MFMA, no Gm staging).
// ---------------------------------------------------------------------------
__global__ __launch_bounds__(512,1) void k_dec_mfma(
    const float* __restrict__ xc, const unsigned short* __restrict__ WdecF,
    const unsigned short* __restrict__ WdihF, const unsigned short* __restrict__ WoutF,
    const float* __restrict__ dbih, const float* __restrict__ dbhh,
    const float* __restrict__ outb, float* __restrict__ out)
{
  __shared__ __align__(16) unsigned char Hb[2][4096];   // h bf16, swizzled, dbuf
  __shared__ __align__(16) unsigned char Xb[16*256];    // xc bf16 [s][128] swizzled
  const int tid = threadIdx.x;
  const int g   = tid >> 6;        // wave 0..7
  const int l   = tid & 63;
  const int lr  = l & 15, lg = l >> 4;
  const int n0  = blockIdx.x * 16;
  const int i   = g*16 + lr;       // owned h column (0..127)

  // stage xc tile as bf16 swizzled A-tile (K padded 112->128 with zeros)
  if (tid < 256){
    int row = tid >> 4, c16 = tid & 15;
    uint4 v = make_uint4(0,0,0,0);
    if (c16 < 14){
      const float* xp = xc + (size_t)(n0+row)*112 + c16*8;
      float4 f0 = *(const float4*)(xp);
      float4 f1 = *(const float4*)(xp + 4);
      v = pack8bf(f0, f1);
    }
    *(uint4*)(Xb + ((row*256 + c16*16) ^ ((row&7)<<4))) = v;
  }
  *(uint4*)(&Hb[0][0] + tid*16) = make_uint4(0,0,0,0);  // zero both buffers (8KB)
  __syncthreads();

  const int swz = (lr & 7) << 4;
  int rdo[4];
  #pragma unroll
  for (int kk=0; kk<4; ++kk) rdo[kk] = (lr*256 + kk*64 + lg*16) ^ swz;

  // gi via MFMA: 3 gates x 4 K-steps from Xb (one-time)
  float gi_r[4], gi_z[4], gi_n[4];
  {
    uint4 axq[4];
    #pragma unroll
    for (int kk=0; kk<4; ++kk)
      axq[kk] = *(const uint4*)(Xb + rdo[kk]);
    f32x4 z4 = (f32x4){0.f,0.f,0.f,0.f};
    f32x4 gR = z4, gZ = z4, gN = z4;
    #pragma unroll
    for (int kk=0; kk<4; ++kk){
      uint4 b0 = *(const uint4*)(WdihF + (size_t)(g*12 + 0*4 + kk)*512 + l*8);
      gR = __builtin_amdgcn_mfma_f32_16x16x32_bf16(as_bf16x8(axq[kk]), as_bf16x8(b0), gR, 0,0,0);
    }
    #pragma unroll
    for (int kk=0; kk<4; ++kk){
      uint4 b1 = *(const uint4*)(WdihF + (size_t)(g*12 + 1*4 + kk)*512 + l*8);
      gZ = __builtin_amdgcn_mfma_f32_16x16x32_bf16(as_bf16x8(axq[kk]), as_bf16x8(b1), gZ, 0,0,0);
    }
    #pragma unroll
    for (int kk=0; kk<4; ++kk){
      uint4 b2 = *(const uint4*)(WdihF + (size_t)(g*12 + 2*4 + kk)*512 + l*8);
      gN = __builtin_amdgcn_mfma_f32_16x16x32_bf16(as_bf16x8(axq[kk]), as_bf16x8(b2), gN, 0,0,0);
    }
    const float bi_r = dbih[i], bi_z = dbih[128+i], bi_n = dbih[256+i];
    #pragma unroll
    for (int u=0; u<4; ++u){
      gi_r[u] = gR[u] + bi_r;
      gi_z[u] = gZ[u] + bi_z;
      gi_n[u] = gN[u] + bi_n;
    }
  }
  const float bh_r = dbhh[i], bh_z = dbhh[128+i], bh_n = dbhh[256+i];
  const float obv  = (lr < 5) ? outb[lr] : 0.f;

  uint4 bgf[12];
  #pragma unroll
  for (int f=0; f<12; ++f)
    bgf[f] = *(const uint4*)(WdecF + (size_t)(g*12 + f)*512 + l*8);
  uint4 bof[4];
  #pragma unroll
  for (int kk=0; kk<4; ++kk)
    bof[kk] = *(const uint4*)(WoutF + (size_t)kk*512 + l*8);

  float hreg[4] = {0.f, 0.f, 0.f, 0.f};

  int wro[4];
  #pragma unroll
  for (int u=0; u<4; ++u){
    int s = lg*4 + u;
    wro[u] = (s*256 + i*2) ^ ((s & 7) << 4);
  }

  int cur = 0;
  __syncthreads();

  #pragma unroll 1
  for (int t=0; t<PRED; ++t){
    const unsigned char* hc = Hb[cur];
    uint4 ah[4];
    #pragma unroll
    for (int kk=0; kk<4; ++kk)
      ah[kk] = *(const uint4*)(hc + rdo[kk]);

    f32x4 z4 = (f32x4){0.f,0.f,0.f,0.f};
    f32x4 aRa = z4, aRb = z4, aZa = z4, aZb = z4, aNa = z4, aNb = z4;
    aRa = __builtin_amdgcn_mfma_f32_16x16x32_bf16(as_bf16x8(ah[0]), as_bf16x8(bgf[0]),  aRa, 0,0,0);
    aRa = __builtin_amdgcn_mfma_f32_16x16x32_bf16(as_bf16x8(ah[1]), as_bf16x8(bgf[1]),  aRa, 0,0,0);
    aRb = __builtin_amdgcn_mfma_f32_16x16x32_bf16(as_bf16x8(ah[2]), as_bf16x8(bgf[2]),  aRb, 0,0,0);
    aRb = __builtin_amdgcn_mfma_f32_16x16x32_bf16(as_bf16x8(ah[3]), as_bf16x8(bgf[3]),  aRb, 0,0,0);
    aZa = __builtin_amdgcn_mfma_f32_16x16x32_bf16(as_bf16x8(ah[0]), as_bf16x8(bgf[4]),  aZa, 0,0,0);
    aZa = __builtin_amdgcn_mfma_f32_16x16x32_bf16(as_bf16x8(ah[1]), as_bf16x8(bgf[5]),  aZa, 0,0,0);
    aZb = __builtin_amdgcn_mfma_f32_16x16x32_bf16(as_bf16x8(ah[2]), as_bf16x8(bgf[6]),  aZb, 0,0,0);
    aZb = __builtin_amdgcn_mfma_f32_16x16x32_bf16(as_bf16x8(ah[3]), as_bf16x8(bgf[7]),  aZb, 0,0,0);
    aNa = __builtin_amdgcn_mfma_f32_16x16x32_bf16(as_bf16x8(ah[0]), as_bf16x8(bgf[8]),  aNa, 0,0,0);
    aNa = __builtin_amdgcn_mfma_f32_16x16x32_bf16(as_bf16x8(ah[1]), as_bf16x8(bgf[9]),  aNa, 0,0,0);
    aNb = __builtin_amdgcn_mfma_f32_16x16x32_bf16(as_bf16x8(ah[2]), as_bf16x8(bgf[10]), aNb, 0,0,0);
    aNb = __builtin_amdgcn_mfma_f32_16x16x32_bf16(as_bf16x8(ah[3]), as_bf16x8(bgf[11]), aNb, 0,0,0);

    if (t > 0 && g == (t & 7)){
      f32x4 accO = z4;
      #pragma unroll
      for (int kk=0; kk<4; ++kk)
        accO = __builtin_amdgcn_mfma_f32_16x16x32_bf16(as_bf16x8(ah[kk]), as_bf16x8(bof[kk]), accO, 0,0,0);
      if (lr < 5){
        #pragma unroll
        for (int u=0; u<4; ++u){
          float a = accO[u] + obv;
          float val = (lr < 2) ? a : (lr == 4 ? tanhf_(a) : __expf(a));
          out[((size_t)(t-1)*NAg + n0 + lg*4 + u)*5 + lr] = val;
        }
      }
    }

    f32x4 aR = aRa + aRb;
    f32x4 aZ = aZa + aZb;
    f32x4 aN = aNa + aNb;

    unsigned char* hn = Hb[cur^1];
    #pragma unroll
    for (int u=0; u<4; ++u){
      float r  = sigf(gi_r[u] + aR[u] + bh_r);
      float z  = sigf(gi_z[u] + aZ[u] + bh_z);
      float nn = tanh2f(fmaf(r, aN[u] + bh_n, gi_n[u]));
      float h  = fmaf(z, hreg[u] - nn, nn);
      hreg[u] = h;
      *(unsigned short*)(hn + wro[u]) = f2bf(h);
    }
    LBAR();
    cur ^= 1;
  }

  // tail: out head for h_PRED (step PRED-1)
  if (g == (PRED & 7)){
    const unsigned char* hc = Hb[cur];
    uint4 ah[4];
    #pragma unroll
    for (int kk=0; kk<4; ++kk)
      ah[kk] = *(const uint4*)(hc + rdo[kk]);
    f32x4 accO = (f32x4){0.f,0.f,0.f,0.f};
    #pragma unroll
    for (int kk=0; kk<4; ++kk)
      accO = __builtin_amdgcn_mfma_f32_16x16x32_bf16(as_bf16x8(ah[kk]), as_bf16x8(bof[kk]), accO, 0,0,0);
    if (lr < 5){
      #pragma unroll
      for (int u=0; u<4; ++u){
        float a = accO[u] + obv;
        float val = (lr < 2) ? a : (lr == 4 ? tanhf_(a) : __expf(a));
        out[((size_t)(PRED-1)*NAg + n0 + lg*4 + u)*5 + lr] = val;
      }
    }
  }
}

// ---------------------------------------------------------------------------
extern "C" void kernel_launch(void* const* d_in, const int* in_sizes, int n_in,
                              void* d_out, int out_size, void* d_ws, size_t ws_size,
                              hipStream_t stream)
{
  const float* x      = (const float*)d_in[0];
  const float* ngbrs  = (const float*)d_in[1];
  const float* graphs = (const float*)d_in[2];
  const void*  masks  = d_in[3];
  // d_in[4] = ngbrs_idx (unused by the reference computation)
  const float* dynW   = (const float*)d_in[5];
  const float* dynb   = (const float*)d_in[6];
  const float* eWih   = (const float*)d_in[7];
  const float* eWhh   = (const float*)d_in[8];
  const float* ebih   = (const float*)d_in[9];
  const float* ebhh   = (const float*)d_in[10];
  const float* sW     = (const float*)d_in[11];
  const float* sb     = (const float*)d_in[12];
  const float* hidW   = (const float*)d_in[13];
  const float* hidb   = (const float*)d_in[14];
  const float* socW   = (const float*)d_in[15];
  const float* socb   = (const float*)d_in[16];
  const float* c31W   = (const float*)d_in[17];
  const float* c31b   = (const float*)d_in[18];
  const float* dWih   = (const float*)d_in[19];
  const float* dWhh   = (const float*)d_in[20];
  const float* dbih   = (const float*)d_in[21];
  const float* dbhh   = (const float*)d_in[22];
  const float* outW   = (const float*)d_in[23];
  const float* outb   = (const float*)d_in[24];
  float* out = (float*)d_out;

  char* ws = (char*)d_ws;
  size_t off = 0;
  __hip_bfloat16* E = (__hip_bfloat16*)(ws + off); off += (size_t)T_OBS*SEQ*64*2;   // 75.5 MB
  float* h_all      = (float*)(ws + off);          off += (size_t)SEQ*64*4;          // 9.4 MB
  int*   cells      = (int*)(ws + off);            off += (size_t)NAg*8*4;
  float* xc         = (float*)(ws + off);          off += (size_t)NAg*112*4;
  unsigned short* Wpk = (unsigned short*)(ws + off); off += (size_t)48*512*2;
  unsigned short* WdecF = (unsigned short*)(ws + off); off += (size_t)96*512*2;
  unsigned short* WoutF = (unsigned short*)(ws + off); off += (size_t)4*512*2;
  unsigned short* SWF = (unsigned short*)(ws + off); off += (size_t)16*512*2;
  unsigned short* WsocF = (unsigned short*)(ws + off); off += (size_t)72*512*2;
  unsigned short* WdihF = (unsigned short*)(ws + off); off += (size_t)96*512*2;

  k_decode_masks<<<1024, 256, 0, stream>>>(masks, cells);
  k_prep<<<192, 256, 0, stream>>>(eWih, eWhh, Wpk, dWhh, WdecF, outW, WoutF, sW, SWF, socW, WsocF, dWih, WdihF);
  k_embed_x<<<2048, 256, 0, stream>>>(x, dynW, dynb, E);
  k_embed_agg_mfma<<<4096, 256, 0, stream>>>(ngbrs, graphs, dynW, dynb, SWF, sb, E);
  k_gru_enc_mfma<<<2304, 256, 0, stream>>>((const unsigned short*)E, Wpk, ebih, ebhh, h_all);
  k_soc_mfma<<<512, 256, 0, stream>>>(h_all, cells, WsocF, socb, c31W, c31b, hidW, hidb, xc);
  k_dec_mfma<<<256, 512, 0, stream>>>(xc, WdecF, WdihF, WoutF, dbih, dbhh, outb, out);
}

// Round 21
// 180.563 us; speedup vs baseline: 1.0790x; 1.0790x over previous
//
#include <hip/hip_runtime.h>
#include <hip/hip_bf16.h>

#define T_OBS 16
#define NAg   4096
#define Vn    8
#define NV    32768           // NAg*Vn
#define SEQ   36864           // NAg + NV
#define PRED  25

typedef __bf16 bf16x8 __attribute__((ext_vector_type(8)));
typedef float  f32x4  __attribute__((ext_vector_type(4)));

// light barrier: LDS-only drain, leaves vmcnt (global loads/stores) in flight.
#define LBAR() do {                                        \
    asm volatile("s_waitcnt lgkmcnt(0)" ::: "memory");     \
    __builtin_amdgcn_s_barrier();                          \
    __builtin_amdgcn_sched_barrier(0);                     \
  } while (0)

__device__ __forceinline__ float leakyf(float v){ return v >= 0.f ? v : 0.1f*v; }
// fast sigmoid/tanh: v_rcp_f32 (~1 ulp) instead of IEEE divide (~10 instrs)
__device__ __forceinline__ float sigf(float x){
  return __builtin_amdgcn_rcpf(1.f + __expf(-x));
}
__device__ __forceinline__ float tanh2f(float x){
  return fmaf(2.f, __builtin_amdgcn_rcpf(1.f + __expf(-2.f*x)), -1.f);
}
__device__ __forceinline__ float tanhf_(float x){
  x = fminf(fmaxf(x, -10.f), 10.f);
  float e = __expf(2.f*x);
  return (e-1.f)*__builtin_amdgcn_rcpf(e+1.f);
}
__device__ __forceinline__ float bf2f(unsigned short u){
  union{unsigned int i; float f;} v; v.i = ((unsigned int)u)<<16; return v.f;
}
__device__ __forceinline__ unsigned short f2bf(float f){
  __hip_bfloat16 b = __float2bfloat16(f);
  return *reinterpret_cast<unsigned short*>(&b);
}
__device__ __forceinline__ float dot4f(float4 a, float4 b, float acc){
  return fmaf(a.x,b.x, fmaf(a.y,b.y, fmaf(a.z,b.z, fmaf(a.w,b.w, acc))));
}
__device__ __forceinline__ bf16x8 as_bf16x8(uint4 u){
  union { uint4 a; bf16x8 b; } v; v.a = u; return v.b;
}
__device__ __forceinline__ uint4 pack8bf(float4 a, float4 b){
  union{ unsigned short s[8]; uint4 u; } o;
  o.s[0]=f2bf(a.x); o.s[1]=f2bf(a.y); o.s[2]=f2bf(a.z); o.s[3]=f2bf(a.w);
  o.s[4]=f2bf(b.x); o.s[5]=f2bf(b.y); o.s[6]=f2bf(b.z); o.s[7]=f2bf(b.w);
  return o.u;
}

// ---------------------------------------------------------------------------
// Decode bool masks -> per-agent 8 cell indices (validated R15, wave/agent).
// ---------------------------------------------------------------------------
__global__ void k_decode_masks(const void* __restrict__ masks, int* __restrict__ cells){
  const int tid = threadIdx.x;
  const int a   = tid >> 6;          // wave in block (4 agents/block)
  const int l   = tid & 63;
  const int n   = blockIdx.x*4 + a;
  const unsigned char* m8  = (const unsigned char*)masks;
  const int*           m32 = (const int*)masks;
  bool sel8 = false, sel32 = false;
  if (l < 39){
    size_t base = ((size_t)n*39 + l)*64;
    sel8  = m8[base] && m8[base+1] && m8[base+33];
    sel32 = m32[base] != 0;
  }
  unsigned long long b8  = __ballot(sel8);
  unsigned long long b32 = __ballot(sel32);
  unsigned long long m = (__popcll(b8) == 8) ? b8 : b32;
  int cnt = __popcll(m);
  if (l < 8 && l >= cnt) cells[n*8 + l] = 0;           // default fill (disjoint slots)
  bool sel = (m >> l) & 1ull;
  int prefix = __popcll(m & ((1ull << l) - 1ull));
  if (sel && prefix < 8) cells[n*8 + prefix] = l;
}

// ---------------------------------------------------------------------------
// One-shot weight re-layouts (validated R14).
// ---------------------------------------------------------------------------
__global__ void k_prep(const float* __restrict__ eWih, const float* __restrict__ eWhh,
                       unsigned short* __restrict__ Wpk,
                       const float* __restrict__ dWhh, unsigned short* __restrict__ WdecF,
                       const float* __restrict__ outW, unsigned short* __restrict__ WoutF,
                       const float* __restrict__ sW, unsigned short* __restrict__ SWF,
                       const float* __restrict__ socW, unsigned short* __restrict__ WsocF,
                       const float* __restrict__ dWih, unsigned short* __restrict__ WdihF){
  int idx = blockIdx.x*blockDim.x + threadIdx.x;   // 49152 threads
  if (idx < 24576){                                // encoder: 48 frags * 512
    int f   = idx >> 9;
    int rem = idx & 511;
    int l   = rem >> 3, j = rem & 7;
    int lr  = l & 15, lg = l >> 4;
    float val;
    if (f < 32){
      int nt = f >> 2, kk = f & 3;
      int n  = nt*16 + lr;                         // rows 0..127 = r,z gates
      int k  = kk*32 + lg*8 + j;
      val = (k < 64) ? eWih[(size_t)n*64 + k] : eWhh[(size_t)n*64 + (k-64)];
    } else if (f < 40){
      int q = f - 32;
      int n = (8 + (q>>1))*16 + lr;                // rows 128..191 = n gate
      int k = (q&1)*32 + lg*8 + j;
      val = eWih[(size_t)n*64 + k];
    } else {
      int q = f - 40;
      int n = (8 + (q>>1))*16 + lr;
      int k = (q&1)*32 + lg*8 + j;
      val = eWhh[(size_t)n*64 + k];
    }
    Wpk[f*512 + l*8 + j] = f2bf(val);
  }
  if (idx < 49152){                                // decoder Whh: 96 frags * 512
    int f   = idx >> 9;                            // g*12 + gate*4 + kk
    int rem = idx & 511;
    int l   = rem >> 3, j = rem & 7;
    int lr  = l & 15, lg = l >> 4;
    int g = f/12, loc = f%12, gate = loc>>2, kk = loc&3;
    int n = gate*128 + g*16 + lr;
    int k = kk*32 + lg*8 + j;
    WdecF[idx] = f2bf(dWhh[(size_t)n*128 + k]);
  }
  if (idx < 49152){                                // decoder Wih: 96 frags * 512
    int f   = idx >> 9;                            // g*12 + gate*4 + kk
    int rem = idx & 511;
    int l   = rem >> 3, j = rem & 7;
    int lr  = l & 15, lg = l >> 4;
    int g = f/12, loc = f%12, gate = loc>>2, kk = loc&3;
    int n = gate*128 + g*16 + lr;
    int k = kk*32 + lg*8 + j;
    WdihF[idx] = (k < 112) ? f2bf(dWih[(size_t)n*112 + k]) : (unsigned short)0;
  }
  if (idx < 2048){                                 // out head: 4 frags * 512
    int kk  = idx >> 9;
    int rem = idx & 511;
    int l   = rem >> 3, j = rem & 7;
    int lr  = l & 15, lg = l >> 4;
    int k = kk*32 + lg*8 + j;
    float v = (lr < 5) ? outW[(size_t)lr*128 + k] : 0.f;
    WoutF[idx] = f2bf(v);
  }
  if (idx < 8192){                                 // s_W: 16 frags * 512
    int f   = idx >> 9;                            // nt*2 + kk
    int rem = idx & 511;
    int l   = rem >> 3, j = rem & 7;
    int lr  = l & 15, lg = l >> 4;
    int nt = f >> 1, kk = f & 1;
    int nn = nt*16 + lr;
    int k  = kk*32 + lg*8 + j;
    SWF[idx] = f2bf(sW[(size_t)nn*64 + k]);
  }
  if (idx < 36864){                                // soc conv1: 72 frags * 512
    int f   = idx >> 9;                            // (w*9+kk)*2+ks
    int rem = idx & 511;
    int l   = rem >> 3, j = rem & 7;
    int lr  = l & 15, lg = l >> 4;
    int w = f/18, loc = f%18, kk = loc>>1, ks = loc&1;
    int o = w*16 + lr;
    int c = ks*32 + lg*8 + j;
    WsocF[idx] = f2bf(socW[(size_t)o*576 + c*9 + kk]);
  }
}

// ---------------------------------------------------------------------------
// x_e = leaky(x @ dyn_W.T + dyn_b) -> E (bf16). One thread per (t,s,c8).
// ---------------------------------------------------------------------------
__global__ void k_embed_x(const float* __restrict__ x, const float* __restrict__ dynW,
                          const float* __restrict__ dynb, __hip_bfloat16* __restrict__ E){
  __shared__ float2 dwL[64];
  __shared__ float  dbL[64];
  const int tid = threadIdx.x;
  if (tid < 64){ dwL[tid] = *(const float2*)(dynW + tid*2); dbL[tid] = dynb[tid]; }
  __syncthreads();

  int idx = blockIdx.x*256 + tid;                  // 16*4096*8 exactly
  int c8 = idx & 7;
  int s  = (idx >> 3) & 4095;
  int t  = idx >> 15;
  float2 xy = *(const float2*)(x + ((size_t)t*NAg + s)*2);
  union { unsigned short sh[8]; uint4 u; } ou;
  #pragma unroll
  for (int jj=0; jj<8; ++jj){
    int c = c8*8 + jj;
    ou.sh[jj] = f2bf(leakyf(fmaf(xy.x, dwL[c].x, fmaf(xy.y, dwL[c].y, dbL[c]))));
  }
  *(uint4*)((unsigned short*)E + ((size_t)t*SEQ + s)*64 + c8*8) = ou.u;
}

// ---------------------------------------------------------------------------
// Per agent n (fused, MFMA): ng_e -> H = ng_e@sW.T+sb -> graph einsum -> E.
// R17/R20 best state: f32 hm [tv][132] with t-XOR bank swizzle, LB(256,2).
// ---------------------------------------------------------------------------
__global__ __launch_bounds__(256,2) void k_embed_agg_mfma(
    const float* __restrict__ ngbrs, const float* __restrict__ graphs,
    const float* __restrict__ dynW, const float* __restrict__ dynb,
    const unsigned short* __restrict__ SWF, const float* __restrict__ sb,
    __hip_bfloat16* __restrict__ E)
{
  __shared__ __align__(16) unsigned char smem[128*132*4];  // 67.6 KB union region
  __shared__ float2 pL[128];
  __shared__ __align__(16) float gL[128];
  __shared__ float2 dwL[64];
  __shared__ float  dbL[64];
  unsigned char* ngeb = smem;            // bf16 [row][64] swizzled (16 KB), GEMM phase
  float*         hm   = (float*)smem;    // f32 [tv][132] (t-XOR swizzled), einsum phase
  const int tid = threadIdx.x;
  const int n = blockIdx.x;

  if (tid < 128) gL[tid] = graphs[(size_t)n*128 + tid];
  if (tid < 64)  dwL[tid] = *(const float2*)(dynW + tid*2);
  if (tid < 64)  dbL[tid] = dynb[tid];
  if (tid < 128){
    int t = tid >> 3, v = tid & 7;
    pL[tid] = *(const float2*)(ngbrs + ((size_t)t*NV + (size_t)n*8 + v)*2);
  }
  __syncthreads();

  #pragma unroll
  for (int p=0; p<4; ++p){
    int chunk = tid + p*256;          // 1024: row*8 + c8
    int row = chunk >> 3, c8 = chunk & 7;
    float2 xy = pL[row];
    union { unsigned short s[8]; uint4 u; } ou;
    #pragma unroll
    for (int jj=0; jj<8; ++jj){
      int c = c8*8 + jj;
      ou.s[jj] = f2bf(leakyf(fmaf(xy.x, dwL[c].x, fmaf(xy.y, dwL[c].y, dbL[c]))));
    }
    *(uint4*)(ngeb + ((row*128 + c8*16) ^ ((row&7)<<4))) = ou.u;
  }
  __syncthreads();

  const int w4 = tid >> 6, l = tid & 63, lr = l & 15, lg = l >> 4;
  f32x4 acc[2][8];
  {
    uint4 bsw[16];
    #pragma unroll
    for (int f=0; f<16; ++f) bsw[f] = *(const uint4*)(SWF + f*512 + l*8);
    float sbv[8];
    #pragma unroll
    for (int nt=0; nt<8; ++nt) sbv[nt] = sb[nt*16 + lr];

    #pragma unroll
    for (int m=0; m<2; ++m)
      #pragma unroll
      for (int nt=0; nt<8; ++nt)
        acc[m][nt] = (f32x4){sbv[nt], sbv[nt], sbv[nt], sbv[nt]};

    #pragma unroll
    for (int m=0; m<2; ++m){
      int row = (w4*2+m)*16 + lr;
      int rb = row*128, sz = (row&7)<<4;
      uint4 a0 = *(const uint4*)(ngeb + ((rb      + lg*16) ^ sz));
      uint4 a1 = *(const uint4*)(ngeb + ((rb + 64 + lg*16) ^ sz));
      bf16x8 A0 = as_bf16x8(a0), A1 = as_bf16x8(a1);
      #pragma unroll
      for (int nt=0; nt<8; ++nt){
        acc[m][nt] = __builtin_amdgcn_mfma_f32_16x16x32_bf16(A0, as_bf16x8(bsw[nt*2+0]), acc[m][nt], 0,0,0);
        acc[m][nt] = __builtin_amdgcn_mfma_f32_16x16x32_bf16(A1, as_bf16x8(bsw[nt*2+1]), acc[m][nt], 0,0,0);
      }
    }
  }
  __syncthreads();                       // all ngeb reads complete; region -> hm

  // hm write with t-XOR swizzle: col q-granule (4 floats) XOR (row>>3)&7
  #pragma unroll
  for (int m=0; m<2; ++m)
    #pragma unroll
    for (int nt=0; nt<8; ++nt)
      #pragma unroll
      for (int jj=0; jj<4; ++jj){
        int row = (w4*2+m)*16 + lg*4 + jj;
        int col = nt*16 + lr;
        int q = (col >> 2) ^ ((row >> 3) & 7);
        hm[row*132 + (q<<2) + (col & 3)] = acc[m][nt][jj];
      }
  __syncthreads();

  // einsum: thread (t = tid>>4, c4 = tid&15); 8 wv outputs of 4 floats each
  {
    int t = tid >> 4, c4 = tid & 15;
    float a4[8][4];
    #pragma unroll
    for (int wv=0; wv<8; ++wv)
      #pragma unroll
      for (int jo=0; jo<4; ++jo) a4[wv][jo] = 0.f;

    #pragma unroll
    for (int k=0; k<2; ++k)
      #pragma unroll
      for (int v=0; v<8; ++v){
        int row = t*8 + v;
        int nq  = (k*16 + c4) ^ (t & 7);           // (col>>2) ^ (row>>3)&7
        float4 h4 = *(const float4*)(hm + row*132 + (nq<<2));
        float4 g0 = *(const float4*)(gL + k*64 + v*8);
        float4 g1 = *(const float4*)(gL + k*64 + v*8 + 4);
        const float* ga = &g0.x;
        const float* gb = &g1.x;
        #pragma unroll
        for (int q=0; q<4; ++q){
          a4[q][0]   = fmaf(ga[q], h4.x, a4[q][0]);
          a4[q][1]   = fmaf(ga[q], h4.y, a4[q][1]);
          a4[q][2]   = fmaf(ga[q], h4.z, a4[q][2]);
          a4[q][3]   = fmaf(ga[q], h4.w, a4[q][3]);
          a4[4+q][0] = fmaf(gb[q], h4.x, a4[4+q][0]);
          a4[4+q][1] = fmaf(gb[q], h4.y, a4[4+q][1]);
          a4[4+q][2] = fmaf(gb[q], h4.z, a4[4+q][2]);
          a4[4+q][3] = fmaf(gb[q], h4.w, a4[4+q][3]);
        }
      }

    unsigned short* Eu = (unsigned short*)E;
    #pragma unroll
    for (int wv=0; wv<8; ++wv){
      union { unsigned short s[4]; uint2 u; } ou;
      ou.s[0] = f2bf(a4[wv][0]); ou.s[1] = f2bf(a4[wv][1]);
      ou.s[2] = f2bf(a4[wv][2]); ou.s[3] = f2bf(a4[wv][3]);
      *(uint2*)(Eu + ((size_t)t*SEQ + NAg + (size_t)n*8 + wv)*64 + c4*4) = ou.u;
    }
  }
}

// ---------------------------------------------------------------------------
// Encoder GRU via MFMA, full-gate-per-wave partition (validated R7/R9/R10).
// ---------------------------------------------------------------------------
__global__ __launch_bounds__(256,4) void k_gru_enc_mfma(
    const unsigned short* __restrict__ E,
    const unsigned short* __restrict__ Wpk,
    const float* __restrict__ bih, const float* __restrict__ bhh,
    float* __restrict__ h_all)
{
  __shared__ __align__(16) unsigned char Hb[2][2048];
  const int tid = threadIdx.x;
  const int w  = tid >> 6;         // wave 0..3
  const int l  = tid & 63;
  const int lr = l & 15;           // A row (seq) / D col
  const int lg = l >> 4;
  const size_t s0 = (size_t)blockIdx.x * 16;
  const int i  = w*16 + lr;        // owned h column

  uint4 bf[12];
  #pragma unroll
  for (int q=0; q<4; ++q) bf[q]   = *(const uint4*)(Wpk + (4*w + q)*512 + l*8);
  #pragma unroll
  for (int q=0; q<4; ++q) bf[4+q] = *(const uint4*)(Wpk + (16 + 4*w + q)*512 + l*8);
  #pragma unroll
  for (int q=0; q<2; ++q) bf[8+q] = *(const uint4*)(Wpk + (32 + 2*w + q)*512 + l*8);
  #pragma unroll
  for (int q=0; q<2; ++q) bf[10+q]= *(const uint4*)(Wpk + (40 + 2*w + q)*512 + l*8);

  const float b_r = bih[i]     + bhh[i];
  const float b_z = bih[64+i]  + bhh[64+i];
  const float bni = bih[128+i];
  const float bnh = bhh[128+i];

  *(uint4*)(&Hb[0][0] + tid*16) = make_uint4(0,0,0,0);
  __syncthreads();

  float hreg[4] = {0.f,0.f,0.f,0.f};

  const int swz = (lr & 7) << 4;
  const int rd0 = (lr*128      + lg*16) ^ swz;
  const int rd1 = (lr*128 + 64 + lg*16) ^ swz;
  int wro[4];
  #pragma unroll
  for (int u=0; u<4; ++u){
    int s = lg*4 + u;
    wro[u] = (s*128 + i*2) ^ ((s & 7) << 4);
  }

  const unsigned short* ep = E + (s0 + lr)*64 + lg*8;
  uint4 ax0 = *(const uint4*)(ep);
  uint4 ax1 = *(const uint4*)(ep + 32);

  int cur = 0;

  #pragma unroll 1
  for (int t=0; t<T_OBS; ++t){
    const unsigned short* pn = ep + ((t < 15) ? (size_t)SEQ*64 : 0);
    uint4 nx0 = *(const uint4*)(pn);
    uint4 nx1 = *(const uint4*)(pn + 32);

    const unsigned char* hc = Hb[cur];
    uint4 ah0 = *(const uint4*)(hc + rd0);
    uint4 ah1 = *(const uint4*)(hc + rd1);

    bf16x8 Ax0 = as_bf16x8(ax0), Ax1 = as_bf16x8(ax1);
    bf16x8 Ah0 = as_bf16x8(ah0), Ah1 = as_bf16x8(ah1);

    f32x4 z4 = (f32x4){0.f,0.f,0.f,0.f};
    f32x4 aRx = z4, aRh = z4, aZx = z4, aZh = z4, aNI = z4, aNH = z4;

    aRx = __builtin_amdgcn_mfma_f32_16x16x32_bf16(Ax0, as_bf16x8(bf[0]),  aRx, 0,0,0);
    aRx = __builtin_amdgcn_mfma_f32_16x16x32_bf16(Ax1, as_bf16x8(bf[1]),  aRx, 0,0,0);
    aRh = __builtin_amdgcn_mfma_f32_16x16x32_bf16(Ah0, as_bf16x8(bf[2]),  aRh, 0,0,0);
    aRh = __builtin_amdgcn_mfma_f32_16x16x32_bf16(Ah1, as_bf16x8(bf[3]),  aRh, 0,0,0);
    aZx = __builtin_amdgcn_mfma_f32_16x16x32_bf16(Ax0, as_bf16x8(bf[4]),  aZx, 0,0,0);
    aZx = __builtin_amdgcn_mfma_f32_16x16x32_bf16(Ax1, as_bf16x8(bf[5]),  aZx, 0,0,0);
    aZh = __builtin_amdgcn_mfma_f32_16x16x32_bf16(Ah0, as_bf16x8(bf[6]),  aZh, 0,0,0);
    aZh = __builtin_amdgcn_mfma_f32_16x16x32_bf16(Ah1, as_bf16x8(bf[7]),  aZh, 0,0,0);
    aNI = __builtin_amdgcn_mfma_f32_16x16x32_bf16(Ax0, as_bf16x8(bf[8]),  aNI, 0,0,0);
    aNI = __builtin_amdgcn_mfma_f32_16x16x32_bf16(Ax1, as_bf16x8(bf[9]),  aNI, 0,0,0);
    aNH = __builtin_amdgcn_mfma_f32_16x16x32_bf16(Ah0, as_bf16x8(bf[10]), aNH, 0,0,0);
    aNH = __builtin_amdgcn_mfma_f32_16x16x32_bf16(Ah1, as_bf16x8(bf[11]), aNH, 0,0,0);

    f32x4 aR = aRx + aRh;
    f32x4 aZ = aZx + aZh;

    unsigned char* hn = Hb[cur^1];
    #pragma unroll
    for (int u=0; u<4; ++u){
      float r  = sigf(aR[u] + b_r);
      float z  = sigf(aZ[u] + b_z);
      float nn = tanh2f(fmaf(r, aNH[u] + bnh, aNI[u] + bni));
      float h  = fmaf(z, hreg[u] - nn, nn);
      hreg[u]  = h;
      *(unsigned short*)(hn + wro[u]) = f2bf(h);
    }
    LBAR();
    cur ^= 1;
    ax0 = nx0; ax1 = nx1;
    ep = pn;
  }

  #pragma unroll
  for (int u=0; u<4; ++u)
    h_all[(s0 + lg*4 + u)*64 + i] = hreg[u];
}

// ---------------------------------------------------------------------------
// Social branch via MFMA (validated R5) + fused x_s head.
// ---------------------------------------------------------------------------
__global__ __launch_bounds__(256,3) void k_soc_mfma(
    const float* __restrict__ h_all, const int* __restrict__ cells,
    const unsigned short* __restrict__ WsocF, const float* __restrict__ socb,
    const float* __restrict__ c31W, const float* __restrict__ c31b,
    const float* __restrict__ hidW, const float* __restrict__ hidb,
    float* __restrict__ xc)
{
  __shared__ unsigned short Qb[9*8*64];   // 9 KB  [kk][v][o] bf16
  __shared__ float o1p[4*64*17];          // 17 KB scatter partials (y shifted +2)
  __shared__ float o1[64*12];             // 3 KB  out1 (y 0..10)
  __shared__ float c2p[4*144];            // 2.25 KB conv2 partials
  __shared__ float W2L[64*48];            // 12 KB [o][ky][p]
  __shared__ float socbL[64];
  __shared__ float b2L[16];
  __shared__ int   cellsL[64];            // [a][v]

  const int tid = threadIdx.x;
  const int w  = tid >> 6;
  const int l  = tid & 63;
  const int lr = l & 15, lg = l >> 4;
  const int n0 = blockIdx.x * 8;

  // fused x_s = leaky(h_x @ hid_W.T + hid_b) for this block's 8 agents
  {
    int a = tid >> 5, j = tid & 31;
    const float* h = h_all + (size_t)(n0 + a)*64;
    const float* wv = hidW + (size_t)j*64;
    float acc = hidb[j];
    #pragma unroll
    for (int k4=0; k4<16; ++k4)
      acc = dot4f(*(const float4*)(h + k4*4), *(const float4*)(wv + k4*4), acc);
    xc[(size_t)(n0+a)*112 + j] = leakyf(acc);
  }

  for (int idx=tid; idx<3072; idx+=256){
    int p = idx/192, rem = idx%192, o = rem/3, ky = rem%3;
    W2L[(o*3+ky)*16 + p] = c31W[idx];
  }
  if (tid < 64) socbL[tid] = socb[tid];
  if (tid < 16) b2L[tid]  = c31b[tid];
  if (tid < 64) cellsL[tid] = cells[n0*8 + tid];

  uint4 bs[18];
  #pragma unroll
  for (int f=0; f<18; ++f)
    bs[f] = *(const uint4*)(WsocF + (size_t)(w*18 + f)*512 + l*8);
  __syncthreads();

  #pragma unroll 1
  for (int a=0; a<8; ++a){
    uint4 ax0u = make_uint4(0,0,0,0), ax1u = make_uint4(0,0,0,0);
    if (lr < 8){
      const float* hp = h_all + ((size_t)NAg + (size_t)(n0+a)*8 + lr)*64 + lg*8;
      float4 f0 = *(const float4*)(hp);
      float4 f1 = *(const float4*)(hp + 4);
      float4 f2 = *(const float4*)(hp + 32);
      float4 f3 = *(const float4*)(hp + 36);
      ax0u = pack8bf(f0, f1);
      ax1u = pack8bf(f2, f3);
    }
    bf16x8 A0 = as_bf16x8(ax0u), A1 = as_bf16x8(ax1u);

    f32x4 acc[9];
    #pragma unroll
    for (int kk=0; kk<9; ++kk) acc[kk] = (f32x4){0.f,0.f,0.f,0.f};
    #pragma unroll
    for (int kk=0; kk<9; ++kk){
      acc[kk] = __builtin_amdgcn_mfma_f32_16x16x32_bf16(A0, as_bf16x8(bs[kk*2+0]), acc[kk], 0,0,0);
      acc[kk] = __builtin_amdgcn_mfma_f32_16x16x32_bf16(A1, as_bf16x8(bs[kk*2+1]), acc[kk], 0,0,0);
    }

    __syncthreads();

    if (lg < 2){
      #pragma unroll
      for (int kk=0; kk<9; ++kk)
        #pragma unroll
        for (int j=0; j<4; ++j)
          Qb[(kk*8 + lg*4 + j)*64 + w*16 + lr] = f2bf(acc[kk][j]);
    }
    for (int idx=tid; idx<2816; idx+=256){
      int q = idx/704, r = idx%704;
      int o = r/11, y = r%11;
      o1p[(q*64 + o)*17 + y + 2] = 0.f;
    }
    __syncthreads();

    {
      int o = tid & 63, q = tid >> 6;
      #pragma unroll
      for (int p6=0; p6<6; ++p6){
        int pr = q*6 + p6;
        int v = pr/3, ky = pr%3;
        int cc = cellsL[a*8 + v];
        int gw = cc/13, gh = cc - gw*13;
        float val = bf2f(Qb[((ky*3+gw)*8 + v)*64 + o]);
        o1p[(q*64 + o)*17 + (gh - ky + 2)] += val;
      }
    }
    __syncthreads();

    for (int idx=tid; idx<704; idx+=256){
      int o = idx/11, y = idx%11;
      float s = socbL[o];
      #pragma unroll
      for (int q=0; q<4; ++q) s += o1p[(q*64 + o)*17 + y + 2];
      o1[o*12 + y] = leakyf(s);
    }
    __syncthreads();

    {
      int q = tid >> 6, l2 = tid & 63;
      for (int e=l2; e<144; e+=64){
        int p = e & 15, y2 = e >> 4;
        float accv = 0.f;
        #pragma unroll
        for (int oi=0; oi<16; ++oi){
          int oo = q*16 + oi;
          const float* o1r = o1 + oo*12 + y2;
          const float* w2r = W2L + oo*48 + p;
          accv = fmaf(o1r[0], w2r[0], fmaf(o1r[1], w2r[16], fmaf(o1r[2], w2r[32], accv)));
        }
        c2p[q*144 + e] = accv;
      }
    }
    __syncthreads();

    if (tid < 80){
      int p = tid/5, ww = tid%5;
      float v0, v1;
      {
        int y2 = (ww == 0) ? 0 : 2*ww - 1;
        float s = b2L[p];
        #pragma unroll
        for (int q=0; q<4; ++q) s += c2p[q*144 + y2*16 + p];
        v0 = leakyf(s);
      }
      if (ww == 0) v1 = v0;
      else {
        int y2 = 2*ww;
        float s = b2L[p];
        #pragma unroll
        for (int q=0; q<4; ++q) s += c2p[q*144 + y2*16 + p];
        v1 = leakyf(s);
      }
      xc[(size_t)(n0+a)*112 + 32 + p*5 + ww] = fmaxf(v0, v1);
    }
  }
}

// ---------------------------------------------------------------------------
// Decoder GRU via MFMA (validated R14: gi via MFMA, no Gm staging).
// ---------------------------------------------------------------------------
__global__ __launch_bounds__(512,1) void k_dec_mfma(
    const float* __restrict__ xc, const unsigned short* __restrict__ WdecF,
    const unsigned short* __restrict__ WdihF, const unsigned short* __restrict__ WoutF,
    const float* __restrict__ dbih, const float* __restrict__ dbhh,
    const float* __restrict__ outb, float* __restrict__ out)
{
  __shared__ __align__(16) unsigned char Hb[2][4096];   // h bf16, swizzled, dbuf
  __shared__ __align__(16) unsigned char Xb[16*256];    // xc bf16 [s][128] swizzled
  const int tid = threadIdx.x;
  const int g   = tid >> 6;        // wave 0..7
  const int l   = tid & 63;
  const int lr  = l & 15, lg = l >> 4;
  const int n0  = blockIdx.x * 16;
  const int i   = g*16 + lr;       // owned h column (0..127)

  // stage xc tile as bf16 swizzled A-tile (K padded 112->128 with zeros)
  if (tid < 256){
    int row = tid >> 4, c16 = tid & 15;
    uint4 v = make_uint4(0,0,0,0);
    if (c16 < 14){
      const float* xp = xc + (size_t)(n0+row)*112 + c16*8;
      float4 f0 = *(const float4*)(xp);
      float4 f1 = *(const float4*)(xp + 4);
      v = pack8bf(f0, f1);
    }
    *(uint4*)(Xb + ((row*256 + c16*16) ^ ((row&7)<<4))) = v;
  }
  *(uint4*)(&Hb[0][0] + tid*16) = make_uint4(0,0,0,0);  // zero both buffers (8KB)
  __syncthreads();

  const int swz = (lr & 7) << 4;
  int rdo[4];
  #pragma unroll
  for (int kk=0; kk<4; ++kk) rdo[kk] = (lr*256 + kk*64 + lg*16) ^ swz;

  // gi via MFMA: 3 gates x 4 K-steps from Xb (one-time)
  float gi_r[4], gi_z[4], gi_n[4];
  {
    uint4 axq[4];
    #pragma unroll
    for (int kk=0; kk<4; ++kk)
      axq[kk] = *(const uint4*)(Xb + rdo[kk]);
    f32x4 z4 = (f32x4){0.f,0.f,0.f,0.f};
    f32x4 gR = z4, gZ = z4, gN = z4;
    #pragma unroll
    for (int kk=0; kk<4; ++kk){
      uint4 b0 = *(const uint4*)(WdihF + (size_t)(g*12 + 0*4 + kk)*512 + l*8);
      gR = __builtin_amdgcn_mfma_f32_16x16x32_bf16(as_bf16x8(axq[kk]), as_bf16x8(b0), gR, 0,0,0);
    }
    #pragma unroll
    for (int kk=0; kk<4; ++kk){
      uint4 b1 = *(const uint4*)(WdihF + (size_t)(g*12 + 1*4 + kk)*512 + l*8);
      gZ = __builtin_amdgcn_mfma_f32_16x16x32_bf16(as_bf16x8(axq[kk]), as_bf16x8(b1), gZ, 0,0,0);
    }
    #pragma unroll
    for (int kk=0; kk<4; ++kk){
      uint4 b2 = *(const uint4*)(WdihF + (size_t)(g*12 + 2*4 + kk)*512 + l*8);
      gN = __builtin_amdgcn_mfma_f32_16x16x32_bf16(as_bf16x8(axq[kk]), as_bf16x8(b2), gN, 0,0,0);
    }
    const float bi_r = dbih[i], bi_z = dbih[128+i], bi_n = dbih[256+i];
    #pragma unroll
    for (int u=0; u<4; ++u){
      gi_r[u] = gR[u] + bi_r;
      gi_z[u] = gZ[u] + bi_z;
      gi_n[u] = gN[u] + bi_n;
    }
  }
  const float bh_r = dbhh[i], bh_z = dbhh[128+i], bh_n = dbhh[256+i];
  const float obv  = (lr < 5) ? outb[lr] : 0.f;

  uint4 bgf[12];
  #pragma unroll
  for (int f=0; f<12; ++f)
    bgf[f] = *(const uint4*)(WdecF + (size_t)(g*12 + f)*512 + l*8);
  uint4 bof[4];
  #pragma unroll
  for (int kk=0; kk<4; ++kk)
    bof[kk] = *(const uint4*)(WoutF + (size_t)kk*512 + l*8);

  float hreg[4] = {0.f, 0.f, 0.f, 0.f};

  int wro[4];
  #pragma unroll
  for (int u=0; u<4; ++u){
    int s = lg*4 + u;
    wro[u] = (s*256 + i*2) ^ ((s & 7) << 4);
  }

  int cur = 0;
  __syncthreads();

  #pragma unroll 1
  for (int t=0; t<PRED; ++t){
    const unsigned char* hc = Hb[cur];
    uint4 ah[4];
    #pragma unroll
    for (int kk=0; kk<4; ++kk)
      ah[kk] = *(const uint4*)(hc + rdo[kk]);

    f32x4 z4 = (f32x4){0.f,0.f,0.f,0.f};
    f32x4 aRa = z4, aRb = z4, aZa = z4, aZb = z4, aNa = z4, aNb = z4;
    aRa = __builtin_amdgcn_mfma_f32_16x16x32_bf16(as_bf16x8(ah[0]), as_bf16x8(bgf[0]),  aRa, 0,0,0);
    aRa = __builtin_amdgcn_mfma_f32_16x16x32_bf16(as_bf16x8(ah[1]), as_bf16x8(bgf[1]),  aRa, 0,0,0);
    aRb = __builtin_amdgcn_mfma_f32_16x16x32_bf16(as_bf16x8(ah[2]), as_bf16x8(bgf[2]),  aRb, 0,0,0);
    aRb = __builtin_amdgcn_mfma_f32_16x16x32_bf16(as_bf16x8(ah[3]), as_bf16x8(bgf[3]),  aRb, 0,0,0);
    aZa = __builtin_amdgcn_mfma_f32_16x16x32_bf16(as_bf16x8(ah[0]), as_bf16x8(bgf[4]),  aZa, 0,0,0);
    aZa = __builtin_amdgcn_mfma_f32_16x16x32_bf16(as_bf16x8(ah[1]), as_bf16x8(bgf[5]),  aZa, 0,0,0);
    aZb = __builtin_amdgcn_mfma_f32_16x16x32_bf16(as_bf16x8(ah[2]), as_bf16x8(bgf[6]),  aZb, 0,0,0);
    aZb = __builtin_amdgcn_mfma_f32_16x16x32_bf16(as_bf16x8(ah[3]), as_bf16x8(bgf[7]),  aZb, 0,0,0);
    aNa = __builtin_amdgcn_mfma_f32_16x16x32_bf16(as_bf16x8(ah[0]), as_bf16x8(bgf[8]),  aNa, 0,0,0);
    aNa = __builtin_amdgcn_mfma_f32_16x16x32_bf16(as_bf16x8(ah[1]), as_bf16x8(bgf[9]),  aNa, 0,0,0);
    aNb = __builtin_amdgcn_mfma_f32_16x16x32_bf16(as_bf16x8(ah[2]), as_bf16x8(bgf[10]), aNb, 0,0,0);
    aNb = __builtin_amdgcn_mfma_f32_16x16x32_bf16(as_bf16x8(ah[3]), as_bf16x8(bgf[11]), aNb, 0,0,0);

    if (t > 0 && g == (t & 7)){
      f32x4 accO = z4;
      #pragma unroll
      for (int kk=0; kk<4; ++kk)
        accO = __builtin_amdgcn_mfma_f32_16x16x32_bf16(as_bf16x8(ah[kk]), as_bf16x8(bof[kk]), accO, 0,0,0);
      if (lr < 5){
        #pragma unroll
        for (int u=0; u<4; ++u){
          float a = accO[u] + obv;
          float val = (lr < 2) ? a : (lr == 4 ? tanhf_(a) : __expf(a));
          out[((size_t)(t-1)*NAg + n0 + lg*4 + u)*5 + lr] = val;
        }
      }
    }

    f32x4 aR = aRa + aRb;
    f32x4 aZ = aZa + aZb;
    f32x4 aN = aNa + aNb;

    unsigned char* hn = Hb[cur^1];
    #pragma unroll
    for (int u=0; u<4; ++u){
      float r  = sigf(gi_r[u] + aR[u] + bh_r);
      float z  = sigf(gi_z[u] + aZ[u] + bh_z);
      float nn = tanh2f(fmaf(r, aN[u] + bh_n, gi_n[u]));
      float h  = fmaf(z, hreg[u] - nn, nn);
      hreg[u] = h;
      *(unsigned short*)(hn + wro[u]) = f2bf(h);
    }
    LBAR();
    cur ^= 1;
  }

  // tail: out head for h_PRED (step PRED-1)
  if (g == (PRED & 7)){
    const unsigned char* hc = Hb[cur];
    uint4 ah[4];
    #pragma unroll
    for (int kk=0; kk<4; ++kk)
      ah[kk] = *(const uint4*)(hc + rdo[kk]);
    f32x4 accO = (f32x4){0.f,0.f,0.f,0.f};
    #pragma unroll
    for (int kk=0; kk<4; ++kk)
      accO = __builtin_amdgcn_mfma_f32_16x16x32_bf16(as_bf16x8(ah[kk]), as_bf16x8(bof[kk]), accO, 0,0,0);
    if (lr < 5){
      #pragma unroll
      for (int u=0; u<4; ++u){
        float a = accO[u] + obv;
        float val = (lr < 2) ? a : (lr == 4 ? tanhf_(a) : __expf(a));
        out[((size_t)(PRED-1)*NAg + n0 + lg*4 + u)*5 + lr] = val;
      }
    }
  }
}

// ---------------------------------------------------------------------------
extern "C" void kernel_launch(void* const* d_in, const int* in_sizes, int n_in,
                              void* d_out, int out_size, void* d_ws, size_t ws_size,
                              hipStream_t stream)
{
  const float* x      = (const float*)d_in[0];
  const float* ngbrs  = (const float*)d_in[1];
  const float* graphs = (const float*)d_in[2];
  const void*  masks  = d_in[3];
  // d_in[4] = ngbrs_idx (unused by the reference computation)
  const float* dynW   = (const float*)d_in[5];
  const float* dynb   = (const float*)d_in[6];
  const float* eWih   = (const float*)d_in[7];
  const float* eWhh   = (const float*)d_in[8];
  const float* ebih   = (const float*)d_in[9];
  const float* ebhh   = (const float*)d_in[10];
  const float* sW     = (const float*)d_in[11];
  const float* sb     = (const float*)d_in[12];
  const float* hidW   = (const float*)d_in[13];
  const float* hidb   = (const float*)d_in[14];
  const float* socW   = (const float*)d_in[15];
  const float* socb   = (const float*)d_in[16];
  const float* c31W   = (const float*)d_in[17];
  const float* c31b   = (const float*)d_in[18];
  const float* dWih   = (const float*)d_in[19];
  const float* dWhh   = (const float*)d_in[20];
  const float* dbih   = (const float*)d_in[21];
  const float* dbhh   = (const float*)d_in[22];
  const float* outW   = (const float*)d_in[23];
  const float* outb   = (const float*)d_in[24];
  float* out = (float*)d_out;

  char* ws = (char*)d_ws;
  size_t off = 0;
  __hip_bfloat16* E = (__hip_bfloat16*)(ws + off); off += (size_t)T_OBS*SEQ*64*2;   // 75.5 MB
  float* h_all      = (float*)(ws + off);          off += (size_t)SEQ*64*4;          // 9.4 MB
  int*   cells      = (int*)(ws + off);            off += (size_t)NAg*8*4;
  float* xc         = (float*)(ws + off);          off += (size_t)NAg*112*4;
  unsigned short* Wpk = (unsigned short*)(ws + off); off += (size_t)48*512*2;
  unsigned short* WdecF = (unsigned short*)(ws + off); off += (size_t)96*512*2;
  unsigned short* WoutF = (unsigned short*)(ws + off); off += (size_t)4*512*2;
  unsigned short* SWF = (unsigned short*)(ws + off); off += (size_t)16*512*2;
  unsigned short* WsocF = (unsigned short*)(ws + off); off += (size_t)72*512*2;
  unsigned short* WdihF = (unsigned short*)(ws + off); off += (size_t)96*512*2;

  k_decode_masks<<<1024, 256, 0, stream>>>(masks, cells);
  k_prep<<<192, 256, 0, stream>>>(eWih, eWhh, Wpk, dWhh, WdecF, outW, WoutF, sW, SWF, socW, WsocF, dWih, WdihF);
  k_embed_x<<<2048, 256, 0, stream>>>(x, dynW, dynb, E);
  k_embed_agg_mfma<<<4096, 256, 0, stream>>>(ngbrs, graphs, dynW, dynb, SWF, sb, E);
  k_gru_enc_mfma<<<2304, 256, 0, stream>>>((const unsigned short*)E, Wpk, ebih, ebhh, h_all);
  k_soc_mfma<<<512, 256, 0, stream>>>(h_all, cells, WsocF, socb, c31W, c31b, hidW, hidb, xc);
  k_dec_mfma<<<256, 512, 0, stream>>>(xc, WdecF, WdihF, WoutF, dbih, dbhh, outb, out);
}